// Round 4
// baseline (513.345 us; speedup 1.0000x reference)
//
#include <hip/hip_runtime.h>
#include <cstdint>

// ---------------------------------------------------------------------------
// BayesianNetwork: 2x vMF-normalized GEMM(1024x4096x4096) + relu, gaussian
// last layer [4096->5] + log_softmax, plus closed-form scalar terms.
// Strategy: split each f32 operand into bf16 hi+lo; GEMM = hi*hi+hi*lo+lo*hi
// on the 2.5PF bf16 MFMA pipe (no fp32 MFMA on CDNA4). ~2^-17 input precision.
// GEMM tile: BM=64 x BN=128, BK=32, 4 waves (2x2) -> 512 blocks = 2/CU.
// ---------------------------------------------------------------------------

#define NH (-0.9189385332046727)   // -0.5*log(2*pi)
#define DPI 3.141592653589793238462643383279502884

typedef short s16x8 __attribute__((ext_vector_type(8)));
typedef float f32x4 __attribute__((ext_vector_type(4)));

static __device__ __forceinline__ ushort f2bf(float f) {
  uint32_t u = __float_as_uint(f);
  u += 0x7fffu + ((u >> 16) & 1u);   // RNE
  return (ushort)(u >> 16);
}
static __device__ __forceinline__ float bf2f(ushort h) {
  return __uint_as_float(((uint32_t)h) << 16);
}

// global -> LDS direct copy, 16B per lane. LDS dest must be linear in lane id
// (wave-uniform base + lane*16) -- our layouts guarantee this.
static __device__ __forceinline__ void gload16(const void* g, void* l) {
  __builtin_amdgcn_global_load_lds(
      (__attribute__((address_space(1))) void*)g,
      (__attribute__((address_space(3))) void*)l,
      16, 0, 0);
}

// --------------------------- reductions ------------------------------------
// mode 0: sum(x^2); mode 1: sum(log(log1p(exp(x)))). Partials in double.
__global__ void reduce_k(const float* __restrict__ x, int n,
                         double* __restrict__ part, int mode) {
  double a = 0.0;
  const int tid = blockIdx.x * blockDim.x + threadIdx.x;
  const int stride = gridDim.x * blockDim.x;
  const int n4 = n >> 2;
  for (int i = tid; i < n4; i += stride) {
    float4 v = reinterpret_cast<const float4*>(x)[i];
    if (mode == 0) {
      a += (double)v.x * v.x + (double)v.y * v.y +
           (double)v.z * v.z + (double)v.w * v.w;
    } else {
      a += log(log1p(exp((double)v.x)));
      a += log(log1p(exp((double)v.y)));
      a += log(log1p(exp((double)v.z)));
      a += log(log1p(exp((double)v.w)));
    }
  }
  for (int i = (n4 << 2) + tid; i < n; i += stride) {
    float v = x[i];
    a += (mode == 0) ? (double)v * v : log(log1p(exp((double)v)));
  }
  for (int o = 32; o > 0; o >>= 1) a += __shfl_down(a, o);
  __shared__ double red[4];
  if ((threadIdx.x & 63) == 0) red[threadIdx.x >> 6] = a;
  __syncthreads();
  if (threadIdx.x == 0) part[blockIdx.x] = red[0] + red[1] + red[2] + red[3];
}

// --------------------------- scalar finalize -------------------------------
static __device__ double logC_vmf(double d, double kappa) {
  double s  = 0.5 * d - 1.0;
  double x  = kappa / s;
  double sq = sqrt(1.0 + x * x);
  double eta = sq + log(x) - log1p(sq);
  double lb  = s * eta - 0.5 * log(2.0 * DPI * s) - 0.5 * log(sq);
  return d * NH + s * log(kappa) - lb;
}

__global__ void finalize_k(const double* __restrict__ part,
                           const float* lkw1, const float* lkb1,
                           const float* lkw2, const float* lkb2,
                           float* __restrict__ params,
                           float* __restrict__ out_sc) {
  __shared__ double S[8];
  __shared__ double tmp[4];
  const int t = threadIdx.x;
  for (int ai = 0; ai < 8; ai++) {
    double v = part[ai * 512 + t] + part[ai * 512 + t + 256];
    for (int o = 32; o > 0; o >>= 1) v += __shfl_down(v, o);
    if ((t & 63) == 0) tmp[t >> 6] = v;
    __syncthreads();
    if (t == 0) S[ai] = tmp[0] + tmp[1] + tmp[2] + tmp[3];
    __syncthreads();
  }
  if (t == 0) {
    double Sw1 = S[0], Sb1 = S[1], Sw2 = S[2], Sb2 = S[3];
    double Sw3 = S[4], Sb3 = S[5], R6 = S[6], R7 = S[7];
    params[0] = (float)(1.0 / sqrt(Sw1));
    params[1] = (float)(1.0 / sqrt(Sb1));
    params[2] = (float)(1.0 / sqrt(Sw2));
    params[3] = (float)(1.0 / sqrt(Sb2));
    const double dw = 16777216.0, db = 4096.0;
    double kw1 = exp((double)lkw1[0]) + 1e-6;
    double kb1 = exp((double)lkb1[0]) + 1e-6;
    double kw2 = exp((double)lkw2[0]) + 1e-6;
    double kb2 = exp((double)lkb2[0]) + 1e-6;
    // dot(mu, mu) == 1 (sumsq / norm^2); f32-noise there is far below the
    // f32 ulp (~16) of the ~2.3e8-magnitude output.
    double lvp = kw1 + logC_vmf(dw, kw1) + kb1 + logC_vmf(db, kb1)
               + kw2 + logC_vmf(dw, kw2) + kb2 + logC_vmf(db, kb2)
               + 20485.0 * NH - R6 - R7;                 // gaussian layer lvp
    // reference: h stays f64 in h*log(pi); only gammaln's arg goes through f32
    double h64 = (dw + 1.0) * 0.5;                       // 8388608.5
    double hf  = (double)(float)h64;                     // 8388608.0
    double lsa = log(2.0) + h64 * log(DPI) - lgamma(hf);
    double lp  = -4.0 * lsa + 20485.0 * NH - 0.5 * (Sw3 + Sb3);
    out_sc[0] = (float)lvp;
    out_sc[1] = (float)lp;
  }
}

// --------------------------- bf16 hi/lo splitting --------------------------
__global__ void split_plain_k(const float* __restrict__ in,
                              ushort* __restrict__ hi, ushort* __restrict__ lo,
                              int n4) {
  int i = blockIdx.x * blockDim.x + threadIdx.x;
  if (i >= n4) return;
  float4 v = reinterpret_cast<const float4*>(in)[i];
  ushort4 h, l;
  h.x = f2bf(v.x); l.x = f2bf(v.x - bf2f(h.x));
  h.y = f2bf(v.y); l.y = f2bf(v.y - bf2f(h.y));
  h.z = f2bf(v.z); l.z = f2bf(v.z - bf2f(h.z));
  h.w = f2bf(v.w); l.w = f2bf(v.w - bf2f(h.w));
  reinterpret_cast<ushort4*>(hi)[i] = h;
  reinterpret_cast<ushort4*>(lo)[i] = l;
}

// W viewed [K=4096][N=4096] row-major -> WT hi/lo [N][K], scaled by *sp.
// 64(k) x 32(n) tile; ushort2 stores (coalesced 4B/lane).
__global__ void split_transpose_k(const float* __restrict__ in,
                                  const float* __restrict__ sp,
                                  ushort* __restrict__ hi,
                                  ushort* __restrict__ lo) {
  __shared__ float tile[64][33];
  const float s = sp[0];
  const int tx = threadIdx.x, ty = threadIdx.y;  // (32,8)
  const int n0 = blockIdx.x * 32, k0 = blockIdx.y * 64;
#pragma unroll
  for (int r = 0; r < 8; r++)
    tile[ty + r * 8][tx] = in[(size_t)(k0 + ty + r * 8) * 4096 + n0 + tx];
  __syncthreads();
#pragma unroll
  for (int r = 0; r < 4; r++) {
    const int nn = ty + r * 8;
    float v0 = tile[2 * tx][nn] * s;
    float v1 = tile[2 * tx + 1][nn] * s;
    ushort2 h, l;
    h.x = f2bf(v0); l.x = f2bf(v0 - bf2f(h.x));
    h.y = f2bf(v1); l.y = f2bf(v1 - bf2f(h.y));
    size_t o = ((size_t)(n0 + nn) * 4096 + k0 + 2 * tx) >> 1;  // ushort2 index
    reinterpret_cast<ushort2*>(hi)[o] = h;
    reinterpret_cast<ushort2*>(lo)[o] = l;
  }
}

// --------------------------- split-bf16 GEMM -------------------------------
// C[64x128]/block, BK=32, 4 waves (2x2, wave tile 32x64), 3 MFMAs per pair.
// A: [M][K] hi/lo bf16 (K contig). B: [N][K] hi/lo bf16 (K contig).
// epilogue: v = relu(acc + bias[col]*bsc); mode0 -> hi/lo bf16, mode1 -> f32.
__global__ __launch_bounds__(256) void gemm_split_k(
    const ushort* __restrict__ Ahi, const ushort* __restrict__ Alo,
    const ushort* __restrict__ Bhi, const ushort* __restrict__ Blo,
    const float* __restrict__ bias, const float* __restrict__ bsp,
    ushort* __restrict__ Ohi, ushort* __restrict__ Olo,
    float* __restrict__ Of,
    int M, int N, int K, int mode) {
  __shared__ ushort As[2][64 * 32];
  __shared__ ushort Bs[2][128 * 32];
  const int t = threadIdx.x;
  const int lane = t & 63, wid = t >> 6;
  const int wm = wid >> 1, wn = wid & 1;
  const int bm = blockIdx.y, bn = blockIdx.x;
  const int lr = lane & 15, lk = (lane >> 4) * 8;

  f32x4 acc[2][4];
#pragma unroll
  for (int i = 0; i < 2; i++)
#pragma unroll
    for (int j = 0; j < 4; j++) acc[i][j] = (f32x4){0.f, 0.f, 0.f, 0.f};

  const size_t arow = (size_t)(bm * 64) * K;
  const size_t brow = (size_t)(bn * 128) * K;
  const int ar = t >> 2, ac = (t & 3) * 8;      // A: 64 rows x 4 chunks

  for (int k0 = 0; k0 < K; k0 += 32) {
    {
      const size_t ga = arow + (size_t)ar * K + k0 + ac;
      gload16(Ahi + ga, &As[0][t * 8]);
      gload16(Alo + ga, &As[1][t * 8]);
    }
#pragma unroll
    for (int q = 0; q < 2; q++) {
      const int L = q * 256 + t;
      const size_t gb = brow + (size_t)(L >> 2) * K + k0 + (L & 3) * 8;
      gload16(Bhi + gb, &Bs[0][L * 8]);
      gload16(Blo + gb, &Bs[1][L * 8]);
    }
    __syncthreads();
    s16x8 ah[2], al[2], bh[4], bl[4];
#pragma unroll
    for (int i = 0; i < 2; i++) {
      const int ra = (wm * 32 + i * 16 + lr) * 32 + lk;
      ah[i] = *(const s16x8*)&As[0][ra];
      al[i] = *(const s16x8*)&As[1][ra];
    }
#pragma unroll
    for (int j = 0; j < 4; j++) {
      const int rb = (wn * 64 + j * 16 + lr) * 32 + lk;
      bh[j] = *(const s16x8*)&Bs[0][rb];
      bl[j] = *(const s16x8*)&Bs[1][rb];
    }
#pragma unroll
    for (int i = 0; i < 2; i++)
#pragma unroll
      for (int j = 0; j < 4; j++) {
        acc[i][j] = __builtin_amdgcn_mfma_f32_16x16x32_bf16(ah[i], bh[j], acc[i][j], 0, 0, 0);
        acc[i][j] = __builtin_amdgcn_mfma_f32_16x16x32_bf16(ah[i], bl[j], acc[i][j], 0, 0, 0);
        acc[i][j] = __builtin_amdgcn_mfma_f32_16x16x32_bf16(al[i], bh[j], acc[i][j], 0, 0, 0);
      }
    __syncthreads();
  }

  const float bsc = bsp[0];
  const int rb0 = bm * 64 + wm * 32 + (lane >> 4) * 4;
  const int cb0 = bn * 128 + wn * 64 + lr;
#pragma unroll
  for (int j = 0; j < 4; j++) {
    const int col = cb0 + j * 16;
    const float bv = bias[col] * bsc;
#pragma unroll
    for (int i = 0; i < 2; i++) {
#pragma unroll
      for (int r = 0; r < 4; r++) {
        const int row = rb0 + i * 16 + r;
        float v = fmaxf(acc[i][j][r] + bv, 0.0f);
        const size_t o = (size_t)row * N + col;
        if (mode == 0) {
          ushort h = f2bf(v);
          Ohi[o] = h;
          Olo[o] = f2bf(v - bf2f(h));
        } else {
          Of[o] = v;
        }
      }
    }
  }
}

// --------------------------- last layer + log_softmax ----------------------
__global__ void layer3_k(const float* __restrict__ h2,
                         const float* __restrict__ w3,
                         const float* __restrict__ b3,
                         float* __restrict__ out) {
  const int row = blockIdx.x;
  const int t = threadIdx.x;
  const float* hr = h2 + (size_t)row * 4096;
  float a[5] = {0.f, 0.f, 0.f, 0.f, 0.f};
  for (int k = t; k < 4096; k += 256) {
    const float h = hr[k];
#pragma unroll
    for (int o = 0; o < 5; o++) a[o] += h * w3[o * 4096 + k];
  }
#pragma unroll
  for (int o = 0; o < 5; o++)
    for (int s = 32; s > 0; s >>= 1) a[o] += __shfl_down(a[o], s);
  __shared__ float red[4][5];
  if ((t & 63) == 0) {
#pragma unroll
    for (int o = 0; o < 5; o++) red[t >> 6][o] = a[o];
  }
  __syncthreads();
  if (t == 0) {
    float y[5];
#pragma unroll
    for (int o = 0; o < 5; o++)
      y[o] = red[0][o] + red[1][o] + red[2][o] + red[3][o] + b3[o];
    float m = y[0];
    for (int o = 1; o < 5; o++) m = fmaxf(m, y[o]);
    float ssum = 0.f;
    for (int o = 0; o < 5; o++) ssum += expf(y[o] - m);
    const float ls = m + logf(ssum);
    for (int o = 0; o < 5; o++) out[row * 5 + o] = y[o] - ls;
  }
}

// --------------------------- launcher --------------------------------------
extern "C" void kernel_launch(void* const* d_in, const int* in_sizes, int n_in,
                              void* d_out, int out_size, void* d_ws, size_t ws_size,
                              hipStream_t stream) {
  const float* x     = (const float*)d_in[0];
  const float* w1mu  = (const float*)d_in[1];
  const float* lkw1  = (const float*)d_in[2];
  const float* b1mu  = (const float*)d_in[3];
  const float* lkb1  = (const float*)d_in[4];
  const float* w2mu  = (const float*)d_in[5];
  const float* lkw2  = (const float*)d_in[6];
  const float* b2mu  = (const float*)d_in[7];
  const float* lkb2  = (const float*)d_in[8];
  const float* w3mu  = (const float*)d_in[9];
  const float* w3rho = (const float*)d_in[10];
  const float* b3mu  = (const float*)d_in[11];
  const float* b3rho = (const float*)d_in[12];
  float* outp = (float*)d_out;

  // workspace layout (~96.1 MB)
  char* w = (char*)d_ws;
  double* part  = (double*)w;                    // 8 arrays x 512 doubles = 32 KB
  float* params = (float*)(w + 32768);           // inv-norms
  ushort* xhi  = (ushort*)(w + 65536);           // 1024x4096 bf16 (8 MB each)
  ushort* xlo  = xhi  + (size_t)1024 * 4096;
  ushort* h1hi = xlo  + (size_t)1024 * 4096;
  ushort* h1lo = h1hi + (size_t)1024 * 4096;
  ushort* wthi = (ushort*)(h1lo + (size_t)1024 * 4096);   // 4096x4096 bf16 (32 MB each)
  ushort* wtlo = wthi + (size_t)4096 * 4096;
  float*  h2   = (float*)xhi;   // reuse x hi/lo region (x dead after GEMM1), 16 MB

  // 1) reductions for norms / scalar terms
  reduce_k<<<512, 256, 0, stream>>>(w1mu, 16777216, part + 0 * 512, 0);
  reduce_k<<<512, 256, 0, stream>>>(b1mu, 4096,     part + 1 * 512, 0);
  reduce_k<<<512, 256, 0, stream>>>(w2mu, 16777216, part + 2 * 512, 0);
  reduce_k<<<512, 256, 0, stream>>>(b2mu, 4096,     part + 3 * 512, 0);
  reduce_k<<<512, 256, 0, stream>>>(w3mu, 20480,    part + 4 * 512, 0);
  reduce_k<<<512, 256, 0, stream>>>(b3mu, 5,        part + 5 * 512, 0);
  reduce_k<<<512, 256, 0, stream>>>(w3rho, 20480,   part + 6 * 512, 1);
  reduce_k<<<512, 256, 0, stream>>>(b3rho, 5,       part + 7 * 512, 1);
  // 2) scalars: inv-norms + lvp/lp outputs (indices 5120, 5121)
  finalize_k<<<1, 256, 0, stream>>>(part, lkw1, lkb1, lkw2, lkb2,
                                    params, outp + 5120);
  // 3) operand preprocessing (hi/lo split; W transposed to [N][K], norm folded)
  split_plain_k<<<4096, 256, 0, stream>>>(x, xhi, xlo, 1048576);
  split_transpose_k<<<dim3(128, 64), dim3(32, 8), 0, stream>>>(w1mu, params + 0, wthi, wtlo);
  // 4) layer 1: h1 = relu(x @ W1 + b1n)  -> bf16 hi/lo
  gemm_split_k<<<dim3(32, 16), 256, 0, stream>>>(xhi, xlo, wthi, wtlo,
                                                 b1mu, params + 1,
                                                 h1hi, h1lo, nullptr,
                                                 1024, 4096, 4096, 0);
  // 5) layer 2: h2 = relu(h1 @ W2 + b2n) -> f32 (into reused x region)
  split_transpose_k<<<dim3(128, 64), dim3(32, 8), 0, stream>>>(w2mu, params + 2, wthi, wtlo);
  gemm_split_k<<<dim3(32, 16), 256, 0, stream>>>(h1hi, h1lo, wthi, wtlo,
                                                 b2mu, params + 3,
                                                 nullptr, nullptr, h2,
                                                 1024, 4096, 4096, 1);
  // 6) last layer + log_softmax -> out[1024][5]
  layer3_k<<<1024, 256, 0, stream>>>(h2, w3mu, b3mu, outp);
}